// Round 11
// baseline (871.599 us; speedup 1.0000x reference)
//
#include <hip/hip_runtime.h>

typedef unsigned short u16;
typedef __bf16 bf16x4 __attribute__((ext_vector_type(4)));
typedef __bf16 bf16x8 __attribute__((ext_vector_type(8)));
typedef float f32x4 __attribute__((ext_vector_type(4)));

#define MFMA_BF16(a, b, c) __builtin_amdgcn_mfma_f32_16x16x32_bf16((a), (b), (c), 0, 0, 0)
#define COMPILER_FENCE() asm volatile("" ::: "memory")

__device__ __forceinline__ bf16x8 ld_g16(const __bf16* p) {
  return *(const bf16x8*)p;
}
__device__ __forceinline__ bf16x8 ld_s16(const void* base, int byteoff) {
  return *(const bf16x8*)((const char*)base + byteoff);
}

// k4 swizzle: varies with BOTH s&7 and s>>3 so the 8 rows touched by one
// store instruction land in distinct bank groups.
#define SW4(s) ((((s) & 7) ^ (((s) >> 3) & 7)) << 4)

// k4 projection: OUT[o][p] = sum_c W[o][c]*SRC[c][p]; SRC rows 512B, SW4 swizzle.
__device__ __forceinline__ void proj_mfma(const __bf16* __restrict__ Wg,
                                          const char* src, f32x4 (&acc)[4][4],
                                          int w, int lm, int lg)
{
  for (int ks = 0; ks < 8; ++ks) {
    bf16x8 afr[4], bfr[4];
#pragma unroll
    for (int mt = 0; mt < 4; ++mt)
      afr[mt] = ld_g16(Wg + (w * 64 + mt * 16 + lm) * 256 + ks * 32 + lg * 8);
#pragma unroll
    for (int nt = 0; nt < 4; ++nt) {
      int p = nt * 16 + lm;
      bfr[nt] = ld_s16(src, p * 512 + (((ks * 32 + lg * 8) * 2) ^ SW4(p)));
    }
    __builtin_amdgcn_s_setprio(1);
#pragma unroll
    for (int mt = 0; mt < 4; ++mt)
#pragma unroll
      for (int nt = 0; nt < 4; ++nt)
        acc[mt][nt] = MFMA_BF16(afr[mt], bfr[nt], acc[mt][nt]);
    __builtin_amdgcn_s_setprio(0);
  }
}

// ---------------- K0: weight cast + BN folding + parallel betav ----------------
__global__ void k0_setup(const float* __restrict__ wq, const float* __restrict__ wk,
                         const float* __restrict__ wv, const float* __restrict__ wp,
                         const float* __restrict__ g1, const float* __restrict__ b1,
                         const float* __restrict__ m1, const float* __restrict__ v1,
                         const float* __restrict__ g2, const float* __restrict__ b2,
                         const float* __restrict__ m2, const float* __restrict__ v2,
                         __bf16* __restrict__ wqb, __bf16* __restrict__ wkb,
                         __bf16* __restrict__ wvb, __bf16* __restrict__ wpb,
                         float* __restrict__ betav,
                         float* __restrict__ s2o, float* __restrict__ b2o)
{
  const int t = threadIdx.x;
  const int i = blockIdx.x * 256 + t;   // i % 256 == t
  const int c = t;
  float s1 = g1[c] * rsqrtf(v1[c] + 1e-5f);
  wqb[i] = (__bf16)wq[i];
  wkb[i] = (__bf16)wk[i];
  wvb[i] = (__bf16)(wv[i] * s1);        // wv' = wv * s1[c]
  wpb[i] = (__bf16)wp[i];
  float contrib = wv[i] * (b1[c] - m1[c] * s1);
  contrib += __shfl_xor(contrib, 1);
  contrib += __shfl_xor(contrib, 2);
  contrib += __shfl_xor(contrib, 4);
  contrib += __shfl_xor(contrib, 8);
  contrib += __shfl_xor(contrib, 16);
  contrib += __shfl_xor(contrib, 32);
  __shared__ float rb[4];
  if ((t & 63) == 0) rb[t >> 6] = contrib;
  __syncthreads();
  if (t == 0) betav[blockIdx.x] = rb[0] + rb[1] + rb[2] + rb[3];
  if (blockIdx.x == 0) {
    float s2 = g2[t] * rsqrtf(v2[t] + 1e-5f);
    s2o[t] = s2;
    b2o[t] = b2[t] - m2[t] * s2;
  }
}

// ---------------- K_PRE: im2col transpose to swizzled bf16 window tiles ----------
__global__ __launch_bounds__(256, 3) void k_pre(
    const float* __restrict__ xe, const float* __restrict__ xv,
    __bf16* __restrict__ tiles, int hb)
{
  __shared__ __align__(16) __bf16 st[32][788];
  const int t = threadIdx.x;
  const int blk = blockIdx.x;               // [0,1024)
  const int cg = blk & 7;
  const int wh = (blk >> 3) & 15;
  const int bl = blk >> 7;                  // [0,8)
  const int b = hb + bl;
  const int c0 = cg * 32;

  for (int s = 0; s < 2; ++s) {
    const float* src = (s == 0 ? xe : xv) + ((size_t)(b * 256 + c0) * 112 + wh * 7) * 112;
    for (int i = t; i < 6272; i += 256) {
      int cc = i / 196;
      int rem = i - cc * 196;
      f32x4 v = *(const f32x4*)(src + cc * 12544 + rem * 4);
      bf16x4 bv;
#pragma unroll
      for (int j = 0; j < 4; ++j) bv[j] = (__bf16)v[j];
      *(bf16x4*)&st[cc][rem * 4] = bv;
    }
    __syncthreads();
    for (int j = t; j < 3136; j += 256) {
      int row = j >> 2, sub = j & 3;
      int ww = row / 49, p = row - ww * 49;
      int y = p / 7, x = ww * 7 + (p - y * 7);
      int cs = sub * 8;
      bf16x8 v;
#pragma unroll
      for (int q = 0; q < 8; ++q) v[q] = st[cs + q][y * 112 + x];
      int n = (bl * 16 + wh) * 16 + ww;
      size_t off = (size_t)n * 50176 + s * 25088 + p * 512
                 + (((c0 + cs) * 2) ^ ((p & 7) << 4));
      *(bf16x8*)((char*)tiles + off) = v;
    }
    __syncthreads();
  }
}

// ---------------- K1: fused QKV projection + attention, 8 waves/block ----------
// 2x32 KiB buffers, 6 barriers. Pad rows 49..63 are NEVER written (stores
// predicated); fragment reads of those rows see stale garbage which is fully
// masked: S entries in-lane-masked, P rows qp>=49 unread/unstored, v columns
// kp>=49 meet stored-zero P (v clamped so 0*garbage can't be NaN/inf).
__global__ __launch_bounds__(512, 4) void k1_attn(
    const __bf16* __restrict__ tiles,
    const __bf16* __restrict__ wqb, const __bf16* __restrict__ wkb,
    const __bf16* __restrict__ wvb, const float* __restrict__ betav,
    float* __restrict__ xout, int hb)
{
  __shared__ __align__(16) __bf16 B0[16384];  // xe [p][c] -> q [p][o] -> P [qp][h*128+kp]
  __shared__ __align__(16) __bf16 B1[16384];  // xv [p][c] -> k [p][o] -> v [o][kp]

  const int t = threadIdx.x;
  const int n = blockIdx.x;                 // [0,2048) within half
  const int bl = n >> 8, wh = (n >> 4) & 15, ww = n & 15;
  const int b = hb + bl;
  const int y0 = wh * 7, x0 = ww * 7;

  // linear coalesced stage of rows 0..48 (pre-swizzled by k_pre); no pad zeroing
  {
    const char* tb = (const char*)tiles + (size_t)n * 50176;
    for (int j = t; j < 3136; j += 512) {
      bf16x8 v = *(const bf16x8*)(tb + j * 16);
      char* d = (j < 1568) ? ((char*)B0 + j * 16) : ((char*)B1 + (j - 1568) * 16);
      *(bf16x8*)d = v;
    }
  }
  __syncthreads();  // B1: staged data visible

  const int w = t >> 6;                 // wave [0,8)
  const int l = t & 63;
  const int lm = l & 15, lg = l >> 4;
  const int h = w >> 1;                 // head
  const int half = w & 1;               // qp-half within head
  const int ob = w * 32;                // o-band base

  // ---- pass 1 over B0 (xe): qac = wq@xe, vac = wv'@xe ----
  f32x4 vac[2][4] = {};
  {
    f32x4 qac[2][4] = {};
    for (int ks = 0; ks < 8; ++ks) {
      bf16x8 aq[2], av[2], bf[4];
#pragma unroll
      for (int mt = 0; mt < 2; ++mt) {
        int row = (ob + mt * 16 + lm) * 256 + ks * 32 + lg * 8;
        aq[mt] = ld_g16(wqb + row);
        av[mt] = ld_g16(wvb + row);
      }
#pragma unroll
      for (int nt = 0; nt < 4; ++nt) {
        int p = nt * 16 + lm;
        bf[nt] = ld_s16(B0, p * 512 + (((ks * 32 + lg * 8) * 2) ^ ((p & 7) << 4)));
      }
      __builtin_amdgcn_s_setprio(1);
#pragma unroll
      for (int mt = 0; mt < 2; ++mt)
#pragma unroll
        for (int nt = 0; nt < 4; ++nt) {
          qac[mt][nt] = MFMA_BF16(aq[mt], bf[nt], qac[mt][nt]);
          vac[mt][nt] = MFMA_BF16(av[mt], bf[nt], vac[mt][nt]);
        }
      __builtin_amdgcn_s_setprio(0);
    }
    __syncthreads();  // B2: all waves done reading B0 (xe)
    // q -> B0 [p][o] band, rows p<49 only
#pragma unroll
    for (int mt = 0; mt < 2; ++mt)
#pragma unroll
      for (int nt = 0; nt < 4; ++nt) {
        int p = nt * 16 + lm;
        if (nt < 3 || lm == 0) {
          int o0 = ob + mt * 16 + lg * 4;
          bf16x4 v4;
#pragma unroll
          for (int r = 0; r < 4; ++r) v4[r] = (__bf16)qac[mt][nt][r];
          *(bf16x4*)((char*)B0 + p * 512 + ((o0 * 2) ^ ((p & 7) << 4))) = v4;
        }
      }
  }

  // ---- pass 2 over B1 (xv): kac = wk@xv, vac += wv'@xv ----
  {
    f32x4 kac[2][4] = {};
    for (int ks = 0; ks < 8; ++ks) {
      bf16x8 ak[2], av[2], bf[4];
#pragma unroll
      for (int mt = 0; mt < 2; ++mt) {
        int row = (ob + mt * 16 + lm) * 256 + ks * 32 + lg * 8;
        ak[mt] = ld_g16(wkb + row);
        av[mt] = ld_g16(wvb + row);
      }
#pragma unroll
      for (int nt = 0; nt < 4; ++nt) {
        int p = nt * 16 + lm;
        bf[nt] = ld_s16(B1, p * 512 + (((ks * 32 + lg * 8) * 2) ^ ((p & 7) << 4)));
      }
      __builtin_amdgcn_s_setprio(1);
#pragma unroll
      for (int mt = 0; mt < 2; ++mt)
#pragma unroll
        for (int nt = 0; nt < 4; ++nt) {
          kac[mt][nt] = MFMA_BF16(ak[mt], bf[nt], kac[mt][nt]);
          vac[mt][nt] = MFMA_BF16(av[mt], bf[nt], vac[mt][nt]);
        }
      __builtin_amdgcn_s_setprio(0);
    }
    __syncthreads();  // B3: all waves done reading B1 (xv)
    // k -> B1 [p][o] band, rows p<49 only
#pragma unroll
    for (int mt = 0; mt < 2; ++mt)
#pragma unroll
      for (int nt = 0; nt < 4; ++nt) {
        int p = nt * 16 + lm;
        if (nt < 3 || lm == 0) {
          int o0 = ob + mt * 16 + lg * 4;
          bf16x4 v4;
#pragma unroll
          for (int r = 0; r < 4; ++r) v4[r] = (__bf16)kac[mt][nt][r];
          *(bf16x4*)((char*)B1 + p * 512 + ((o0 * 2) ^ ((p & 7) << 4))) = v4;
        }
      }
  }
  __syncthreads();  // B4: q,k visible to all waves

  // ---- S^T via swapped operands: D[kp][qp] (garbage rows -> invalid slots only) ----
  f32x4 sacc[2][4] = {};
  for (int ks = 0; ks < 2; ++ks) {
    bf16x8 aq[2], bk[4];
#pragma unroll
    for (int mt = 0; mt < 2; ++mt) {
      int qp = half * 32 + mt * 16 + lm;
      aq[mt] = ld_s16(B0, qp * 512 + (((h * 64 + ks * 32 + lg * 8) * 2) ^ ((qp & 7) << 4)));
    }
#pragma unroll
    for (int nt = 0; nt < 4; ++nt) {
      int kp = nt * 16 + lm;
      bk[nt] = ld_s16(B1, kp * 512 + (((h * 64 + ks * 32 + lg * 8) * 2) ^ ((kp & 7) << 4)));
    }
    __builtin_amdgcn_s_setprio(1);
#pragma unroll
    for (int mt = 0; mt < 2; ++mt)
#pragma unroll
      for (int nt = 0; nt < 4; ++nt)
        sacc[mt][nt] = MFMA_BF16(bk[nt], aq[mt], sacc[mt][nt]);  // swapped -> D[kp][qp]
    __builtin_amdgcn_s_setprio(0);
  }

  // ---- softmax over kp: in-lane 16 values + 2 shfl rounds ----
  COMPILER_FENCE();
#pragma unroll
  for (int mt = 0; mt < 2; ++mt) {
    float mx = -3.0e38f;
#pragma unroll
    for (int nt = 0; nt < 4; ++nt)
#pragma unroll
      for (int r = 0; r < 4; ++r) {
        float s = sacc[mt][nt][r] * 0.125f;
        sacc[mt][nt][r] = s;
        bool valid = (nt < 3) || (lg == 0 && r == 0);   // kp < 49
        if (valid) mx = fmaxf(mx, s);
      }
    mx = fmaxf(mx, __shfl_xor(mx, 16));
    mx = fmaxf(mx, __shfl_xor(mx, 32));
    float sum = 0.f;
#pragma unroll
    for (int nt = 0; nt < 4; ++nt)
#pragma unroll
      for (int r = 0; r < 4; ++r) {
        bool valid = (nt < 3) || (lg == 0 && r == 0);
        float e = valid ? __expf(sacc[mt][nt][r] - mx) : 0.f;
        sacc[mt][nt][r] = e;
        sum += e;
      }
    sum += __shfl_xor(sum, 16);
    sum += __shfl_xor(sum, 32);
    float inv = 1.f / sum;
    // store P[qp][h*128 + kp], rows qp<49 only (kp>=49 stored as exact zeros)
    int qp = half * 32 + mt * 16 + lm;
    if (qp < 49) {
      int rowb = qp * 512 + h * 128;
      int sw = (qp & 7) << 4;
#pragma unroll
      for (int nt = 0; nt < 4; ++nt) {
        bf16x4 v4;
#pragma unroll
        for (int r = 0; r < 4; ++r) v4[r] = (__bf16)(sacc[mt][nt][r] * inv);
        int kp0 = nt * 16 + lg * 4;
        *(bf16x4*)((char*)B0 + rowb + ((kp0 * 2) ^ sw)) = v4;
      }
    }
  }
  __syncthreads();  // B5: all S reads of B1(k) done before v overwrites it

  // ---- v = clamp(relu(vac + beta), 1e30) -> B1 as [o][kp], rows 128 B ----
  // Clamp kills inf/NaN from garbage pad columns (0*inf hazard in PV).
  {
    float beta[2][4];
#pragma unroll
    for (int mt = 0; mt < 2; ++mt) {
      f32x4 bv = *(const f32x4*)(betav + ob + mt * 16 + lg * 4);
#pragma unroll
      for (int r = 0; r < 4; ++r) beta[mt][r] = bv[r];
    }
#pragma unroll
    for (int mt = 0; mt < 2; ++mt)
#pragma unroll
      for (int nt = 0; nt < 4; ++nt)
#pragma unroll
        for (int r = 0; r < 4; ++r) {
          int o = ob + mt * 16 + lg * 4 + r;
          int kp = nt * 16 + lm;
          float val = fminf(fmaxf(vac[mt][nt][r] + beta[mt][r], 0.f), 1e30f);
          int off = o * 128 + ((kp * 2) ^ ((o & 7) << 4));
          *(__bf16*)((char*)B1 + off) = (__bf16)val;
        }
  }
  __syncthreads();  // B6: v visible

  // ---- x_sp^T via swapped PV: D[o][qp] ----
  f32x4 oacc[4][2] = {};
  for (int ks = 0; ks < 2; ++ks) {
    bf16x8 pf[2], bv[4];
#pragma unroll
    for (int mt = 0; mt < 2; ++mt) {
      int qp = half * 32 + mt * 16 + lm;
      pf[mt] = ld_s16(B0, qp * 512 + h * 128 + (((ks * 32 + lg * 8) * 2) ^ ((qp & 7) << 4)));
    }
#pragma unroll
    for (int nt = 0; nt < 4; ++nt) {
      int o = h * 64 + nt * 16 + lm;
      bv[nt] = ld_s16(B1, o * 128 + (((ks * 32 + lg * 8) * 2) ^ ((o & 7) << 4)));
    }
    __builtin_amdgcn_s_setprio(1);
#pragma unroll
    for (int nt = 0; nt < 4; ++nt)
#pragma unroll
      for (int mt = 0; mt < 2; ++mt)
        oacc[nt][mt] = MFMA_BF16(bv[nt], pf[mt], oacc[nt][mt]);  // swapped -> D[o][qp]
    __builtin_amdgcn_s_setprio(0);
  }

  // ---- store x = IMP * x_sp (fp32); lanes sweep qp -> coalesced 28B runs ----
  const float IMP = (1.0f / 49.0f) / ((1.0f / 49.0f) + 1e-6f);
#pragma unroll
  for (int mt = 0; mt < 2; ++mt) {
    int qp = half * 32 + mt * 16 + lm;
    if (qp < 49) {
      int yy = y0 + qp / 7;
      int xx = x0 + qp % 7;
      size_t pix = (size_t)yy * 112 + xx;
#pragma unroll
      for (int nt = 0; nt < 4; ++nt)
#pragma unroll
        for (int r = 0; r < 4; ++r) {
          int o = h * 64 + nt * 16 + lg * 4 + r;
          xout[(size_t)(b * 256 + o) * 12544 + pix] = IMP * oacc[nt][mt][r];
        }
    }
  }
}

// ---------------- K2: depthwise 3x3 + BN2 + SiLU + pool (sliding reg window) ------
__global__ __launch_bounds__(256, 3) void k2_conv(
    const float* __restrict__ xin, const float* __restrict__ dww,
    const float* __restrict__ bn2s, const float* __restrict__ bn2b,
    __bf16* __restrict__ y1, float* __restrict__ pm)
{
  __shared__ __align__(16) float pl[12544];
  __shared__ float red[4];
  const int bc = blockIdx.x;
  const int c = bc & 255;
  const float* plane = xin + (size_t)bc * 12544;
  const int t = threadIdx.x;
  for (int i = t; i < 3136; i += 256)
    ((f32x4*)pl)[i] = ((const f32x4*)plane)[i];
  float wg[9];
#pragma unroll
  for (int i = 0; i < 9; ++i) wg[i] = dww[c * 9 + i];
  const float sc = bn2s[c], bi = bn2b[c];
  __syncthreads();

  const int x = t & 127;
  const int seg = t >> 7;
  float lsum = 0.f;
  if (x < 112) {
    const bool lok = x > 0, rok = x < 111;
    const int y0 = seg * 56;
    float m0, m1, m2, c0, c1, c2, p0, p1, p2;
    if (y0 == 0) {
      m0 = m1 = m2 = 0.f;
    } else {
      const float* rr = &pl[(y0 - 1) * 112 + x];
      m0 = lok ? rr[-1] : 0.f; m1 = rr[0]; m2 = rok ? rr[1] : 0.f;
    }
    {
      const float* rr = &pl[y0 * 112 + x];
      c0 = lok ? rr[-1] : 0.f; c1 = rr[0]; c2 = rok ? rr[1] : 0.f;
    }
#pragma unroll 4
    for (int y = y0; y < y0 + 56; ++y) {
      if (y < 111) {
        const float* rr = &pl[(y + 1) * 112 + x];
        p0 = lok ? rr[-1] : 0.f; p1 = rr[0]; p2 = rok ? rr[1] : 0.f;
      } else {
        p0 = p1 = p2 = 0.f;
      }
      float acc = m0 * wg[0] + m1 * wg[1] + m2 * wg[2]
                + c0 * wg[3] + c1 * wg[4] + c2 * wg[5]
                + p0 * wg[6] + p1 * wg[7] + p2 * wg[8];
      float u = acc * sc + bi;
      float sl = u / (1.f + __expf(-u));
      y1[(size_t)bc * 12544 + y * 112 + x] = (__bf16)sl;
      lsum += sl;
      m0 = c0; m1 = c1; m2 = c2;
      c0 = p0; c1 = p1; c2 = p2;
    }
  }
  lsum += __shfl_xor(lsum, 1);
  lsum += __shfl_xor(lsum, 2);
  lsum += __shfl_xor(lsum, 4);
  lsum += __shfl_xor(lsum, 8);
  lsum += __shfl_xor(lsum, 16);
  lsum += __shfl_xor(lsum, 32);
  if ((t & 63) == 0) red[t >> 6] = lsum;
  __syncthreads();
  if (t == 0) pm[bc] = (red[0] + red[1] + red[2] + red[3]) * (1.0f / 12544.0f);
}

// ---------------- K3: ECA gate ----------------
__global__ void k3_eca(const float* __restrict__ pm, const float* __restrict__ ecaw,
                       float* __restrict__ gate)
{
  int b = blockIdx.x, c = threadIdx.x;
  float p0 = (c > 0) ? pm[b * 256 + c - 1] : 0.f;
  float p1 = pm[b * 256 + c];
  float p2 = (c < 255) ? pm[b * 256 + c + 1] : 0.f;
  float a = ecaw[0] * p0 + ecaw[1] * p1 + ecaw[2] * p2;
  gate[b * 256 + c] = 1.f / (1.f + __expf(-a));
}

// ---------------- K4: out(fp32, in-place) = x + wp @ (y1 * gate) ----------------
__global__ __launch_bounds__(256, 4) void k4_out(
    const __bf16* __restrict__ y1, const float* __restrict__ gate,
    const __bf16* __restrict__ wpb, float* out_inout)
{
  __shared__ __align__(16) char bt[32768];  // [64 pos][256 ch] bf16, SW4-swizzled
  const int t = threadIdx.x;
  const int blk = blockIdx.x;
  const int b = blk / 196;
  const int s0 = (blk - b * 196) * 64;
  const int chunk = t & 7, crow = t >> 3;
#pragma unroll
  for (int cc = 0; cc < 8; ++cc) {
    int c = cc * 32 + crow;
    float g = gate[b * 256 + c];
    const __bf16* src = y1 + (size_t)(b * 256 + c) * 12544 + s0 + chunk * 8;
    bf16x8 v = *(const bf16x8*)src;
#pragma unroll
    for (int j = 0; j < 8; ++j) {
      int s = chunk * 8 + j;
      float f = (float)v[j] * g;
      *(__bf16*)(bt + s * 512 + ((c * 2) ^ SW4(s))) = (__bf16)f;
    }
  }
  __syncthreads();
  const int w = t >> 6, l = t & 63, lm = l & 15, lg = l >> 4;
  f32x4 acc[4][4] = {};
  proj_mfma(wpb, bt, acc, w, lm, lg);
#pragma unroll
  for (int mt = 0; mt < 4; ++mt)
#pragma unroll
    for (int nt = 0; nt < 4; ++nt)
#pragma unroll
      for (int r = 0; r < 4; ++r) {
        int o = w * 64 + mt * 16 + lg * 4 + r;
        int s = nt * 16 + lm;
        size_t idx = (size_t)(b * 256 + o) * 12544 + s0 + s;
        out_inout[idx] = out_inout[idx] + acc[mt][nt][r];
      }
}

// ---------------- launcher ----------------
extern "C" void kernel_launch(void* const* d_in, const int* in_sizes, int n_in,
                              void* d_out, int out_size, void* d_ws, size_t ws_size,
                              hipStream_t stream) {
  const float* x_edge = (const float*)d_in[0];
  const float* x_vit  = (const float*)d_in[1];
  const float* bn1_g  = (const float*)d_in[2];
  const float* bn1_b  = (const float*)d_in[3];
  const float* bn1_m  = (const float*)d_in[4];
  const float* bn1_v  = (const float*)d_in[5];
  const float* wq     = (const float*)d_in[6];
  const float* wk     = (const float*)d_in[7];
  const float* wv     = (const float*)d_in[8];
  const float* dw_w   = (const float*)d_in[9];
  const float* bn2_g  = (const float*)d_in[10];
  const float* bn2_b  = (const float*)d_in[11];
  const float* bn2_m  = (const float*)d_in[12];
  const float* bn2_v  = (const float*)d_in[13];
  const float* eca_w  = (const float*)d_in[14];
  const float* wp     = (const float*)d_in[15];

  float* out = (float*)d_out;  // reference output dtype is float32

  char* ws = (char*)d_ws;
  __bf16* tiles = (__bf16*)ws;
  __bf16* y1    = (__bf16*)ws;
  const size_t o1 = 102760448;
  __bf16* wqb  = (__bf16*)(ws + o1);
  __bf16* wkb  = (__bf16*)(ws + o1 + 131072);
  __bf16* wvb  = (__bf16*)(ws + o1 + 262144);
  __bf16* wpb  = (__bf16*)(ws + o1 + 393216);
  float*  betav= (float*)(ws + o1 + 524288);
  float*  bn2s = (float*)(ws + o1 + 525312);
  float*  bn2bb= (float*)(ws + o1 + 526336);
  float*  pm   = (float*)(ws + o1 + 527360);
  float*  gate = (float*)(ws + o1 + 543744);

  hipLaunchKernelGGL(k0_setup, dim3(256), dim3(256), 0, stream,
                     wq, wk, wv, wp, bn1_g, bn1_b, bn1_m, bn1_v,
                     bn2_g, bn2_b, bn2_m, bn2_v,
                     wqb, wkb, wvb, wpb, betav, bn2s, bn2bb);
  for (int hb = 0; hb < 16; hb += 8) {
    hipLaunchKernelGGL(k_pre, dim3(1024), dim3(256), 0, stream,
                       x_edge, x_vit, tiles, hb);
    hipLaunchKernelGGL(k1_attn, dim3(2048), dim3(512), 0, stream,
                       tiles, wqb, wkb, wvb, betav, out, hb);
  }
  hipLaunchKernelGGL(k2_conv, dim3(4096), dim3(256), 0, stream,
                     out, dw_w, bn2s, bn2bb, y1, pm);
  hipLaunchKernelGGL(k3_eca, dim3(16), dim3(256), 0, stream, pm, eca_w, gate);
  hipLaunchKernelGGL(k4_out, dim3(3136), dim3(256), 0, stream,
                     y1, gate, wpb, out);
}

// Round 12
// 783.461 us; speedup vs baseline: 1.1125x; 1.1125x over previous
//
#include <hip/hip_runtime.h>

typedef unsigned short u16;
typedef __bf16 bf16x4 __attribute__((ext_vector_type(4)));
typedef __bf16 bf16x8 __attribute__((ext_vector_type(8)));
typedef float f32x4 __attribute__((ext_vector_type(4)));

#define MFMA_BF16(a, b, c) __builtin_amdgcn_mfma_f32_16x16x32_bf16((a), (b), (c), 0, 0, 0)
#define COMPILER_FENCE() asm volatile("" ::: "memory")

__device__ __forceinline__ bf16x8 ld_g16(const __bf16* p) {
  return *(const bf16x8*)p;
}
__device__ __forceinline__ bf16x8 ld_s16(const void* base, int byteoff) {
  return *(const bf16x8*)((const char*)base + byteoff);
}

// Single-weight projection (k4 only): OUT[o][p] = sum_c W[o][c]*SRC[c][p].
__device__ __forceinline__ void proj_mfma(const __bf16* __restrict__ Wg,
                                          const __bf16* src, f32x4 (&acc)[4][4],
                                          int w, int lm, int lg)
{
  for (int ks = 0; ks < 8; ++ks) {
    bf16x8 afr[4], bfr[4];
#pragma unroll
    for (int mt = 0; mt < 4; ++mt)
      afr[mt] = ld_g16(Wg + (w * 64 + mt * 16 + lm) * 256 + ks * 32 + lg * 8);
#pragma unroll
    for (int nt = 0; nt < 4; ++nt) {
      int p = nt * 16 + lm;
      bfr[nt] = ld_s16(src, p * 512 + (((ks * 32 + lg * 8) * 2) ^ ((p & 7) << 4)));
    }
    __builtin_amdgcn_s_setprio(1);
#pragma unroll
    for (int mt = 0; mt < 4; ++mt)
#pragma unroll
      for (int nt = 0; nt < 4; ++nt)
        acc[mt][nt] = MFMA_BF16(afr[mt], bfr[nt], acc[mt][nt]);
    __builtin_amdgcn_s_setprio(0);
  }
}

// ---------------- K0: weight cast + BN folding + parallel betav ----------------
__global__ void k0_setup(const float* __restrict__ wq, const float* __restrict__ wk,
                         const float* __restrict__ wv, const float* __restrict__ wp,
                         const float* __restrict__ g1, const float* __restrict__ b1,
                         const float* __restrict__ m1, const float* __restrict__ v1,
                         const float* __restrict__ g2, const float* __restrict__ b2,
                         const float* __restrict__ m2, const float* __restrict__ v2,
                         __bf16* __restrict__ wqb, __bf16* __restrict__ wkb,
                         __bf16* __restrict__ wvb, __bf16* __restrict__ wpb,
                         float* __restrict__ betav,
                         float* __restrict__ s2o, float* __restrict__ b2o)
{
  const int t = threadIdx.x;
  const int i = blockIdx.x * 256 + t;   // i % 256 == t
  const int c = t;
  float s1 = g1[c] * rsqrtf(v1[c] + 1e-5f);
  wqb[i] = (__bf16)wq[i];
  wkb[i] = (__bf16)wk[i];
  wvb[i] = (__bf16)(wv[i] * s1);        // wv' = wv * s1[c]
  wpb[i] = (__bf16)wp[i];
  float contrib = wv[i] * (b1[c] - m1[c] * s1);
  contrib += __shfl_xor(contrib, 1);
  contrib += __shfl_xor(contrib, 2);
  contrib += __shfl_xor(contrib, 4);
  contrib += __shfl_xor(contrib, 8);
  contrib += __shfl_xor(contrib, 16);
  contrib += __shfl_xor(contrib, 32);
  __shared__ float rb[4];
  if ((t & 63) == 0) rb[t >> 6] = contrib;
  __syncthreads();
  if (t == 0) betav[blockIdx.x] = rb[0] + rb[1] + rb[2] + rb[3];
  if (blockIdx.x == 0) {
    float s2 = g2[t] * rsqrtf(v2[t] + 1e-5f);
    s2o[t] = s2;
    b2o[t] = b2[t] - m2[t] * s2;
  }
}

// ---------------- K_PRE: im2col transpose to swizzled bf16 window tiles ----------
__global__ __launch_bounds__(256, 3) void k_pre(
    const float* __restrict__ xe, const float* __restrict__ xv,
    __bf16* __restrict__ tiles, int hb)
{
  __shared__ __align__(16) __bf16 st[32][788];
  const int t = threadIdx.x;
  const int blk = blockIdx.x;               // [0,1024)
  const int cg = blk & 7;
  const int wh = (blk >> 3) & 15;
  const int bl = blk >> 7;                  // [0,8)
  const int b = hb + bl;
  const int c0 = cg * 32;

  for (int s = 0; s < 2; ++s) {
    const float* src = (s == 0 ? xe : xv) + ((size_t)(b * 256 + c0) * 112 + wh * 7) * 112;
    for (int i = t; i < 6272; i += 256) {
      int cc = i / 196;
      int rem = i - cc * 196;
      f32x4 v = *(const f32x4*)(src + cc * 12544 + rem * 4);
      bf16x4 bv;
#pragma unroll
      for (int j = 0; j < 4; ++j) bv[j] = (__bf16)v[j];
      *(bf16x4*)&st[cc][rem * 4] = bv;
    }
    __syncthreads();
    for (int j = t; j < 3136; j += 256) {
      int row = j >> 2, sub = j & 3;
      int ww = row / 49, p = row - ww * 49;
      int y = p / 7, x = ww * 7 + (p - y * 7);
      int cs = sub * 8;
      bf16x8 v;
#pragma unroll
      for (int q = 0; q < 8; ++q) v[q] = st[cs + q][y * 112 + x];
      int n = (bl * 16 + wh) * 16 + ww;
      size_t off = (size_t)n * 50176 + s * 25088 + p * 512
                 + (((c0 + cs) * 2) ^ ((p & 7) << 4));
      *(bf16x8*)((char*)tiles + off) = v;
    }
    __syncthreads();
  }
}

// ---------------- K1: fused QKV projection + attention, 8 waves/block ----------
// Proven structure: 2x32 KiB buffers, zeroed pads, 6 barriers.
// Wave w: o-band [w*32, w*32+32); head h = w>>1, qp-half = w&1.
__global__ __launch_bounds__(512, 4) void k1_attn(
    const __bf16* __restrict__ tiles,
    const __bf16* __restrict__ wqb, const __bf16* __restrict__ wkb,
    const __bf16* __restrict__ wvb, const float* __restrict__ betav,
    float* __restrict__ xout, int hb)
{
  __shared__ __align__(16) __bf16 B0[16384];  // xe [p][c] -> q [p][o] -> P [qp][h*128+kp]
  __shared__ __align__(16) __bf16 B1[16384];  // xv [p][c] -> k [p][o] -> v [o][kp]

  const int t = threadIdx.x;
  const int n = blockIdx.x;                 // [0,2048) within half
  const int bl = n >> 8, wh = (n >> 4) & 15, ww = n & 15;
  const int b = hb + bl;
  const int y0 = wh * 7, x0 = ww * 7;

  // zero padding rows p=49..63 of both buffers
  for (int idx = t; idx < 15 * 256; idx += 512) {
    int off = (49 + (idx >> 8)) * 512 + (idx & 255) * 2;
    *(__bf16*)((char*)B0 + off) = (__bf16)0.f;
    *(__bf16*)((char*)B1 + off) = (__bf16)0.f;
  }
  // linear coalesced stage (pre-swizzled by k_pre)
  {
    const char* tb = (const char*)tiles + (size_t)n * 50176;
    for (int j = t; j < 3136; j += 512) {
      bf16x8 v = *(const bf16x8*)(tb + j * 16);
      char* d = (j < 1568) ? ((char*)B0 + j * 16) : ((char*)B1 + (j - 1568) * 16);
      *(bf16x8*)d = v;
    }
  }
  __syncthreads();  // B1: staged data visible

  const int w = t >> 6;                 // wave [0,8)
  const int l = t & 63;
  const int lm = l & 15, lg = l >> 4;
  const int h = w >> 1;                 // head
  const int half = w & 1;               // qp-half within head
  const int ob = w * 32;                // o-band base

  // ---- pass 1 over B0 (xe): qac = wq@xe, vac = wv'@xe ----
  f32x4 vac[2][4] = {};
  {
    f32x4 qac[2][4] = {};
    for (int ks = 0; ks < 8; ++ks) {
      bf16x8 aq[2], av[2], bf[4];
#pragma unroll
      for (int mt = 0; mt < 2; ++mt) {
        int row = (ob + mt * 16 + lm) * 256 + ks * 32 + lg * 8;
        aq[mt] = ld_g16(wqb + row);
        av[mt] = ld_g16(wvb + row);
      }
#pragma unroll
      for (int nt = 0; nt < 4; ++nt) {
        int p = nt * 16 + lm;
        bf[nt] = ld_s16(B0, p * 512 + (((ks * 32 + lg * 8) * 2) ^ ((p & 7) << 4)));
      }
      __builtin_amdgcn_s_setprio(1);
#pragma unroll
      for (int mt = 0; mt < 2; ++mt)
#pragma unroll
        for (int nt = 0; nt < 4; ++nt) {
          qac[mt][nt] = MFMA_BF16(aq[mt], bf[nt], qac[mt][nt]);
          vac[mt][nt] = MFMA_BF16(av[mt], bf[nt], vac[mt][nt]);
        }
      __builtin_amdgcn_s_setprio(0);
    }
    __syncthreads();  // B2: all waves done reading B0 (xe)
#pragma unroll
    for (int mt = 0; mt < 2; ++mt)
#pragma unroll
      for (int nt = 0; nt < 4; ++nt) {
        int o0 = ob + mt * 16 + lg * 4;
        int p = nt * 16 + lm;
        bf16x4 v4;
#pragma unroll
        for (int r = 0; r < 4; ++r) v4[r] = (__bf16)qac[mt][nt][r];
        *(bf16x4*)((char*)B0 + p * 512 + ((o0 * 2) ^ ((p & 7) << 4))) = v4;
      }
  }

  // ---- pass 2 over B1 (xv): kac = wk@xv, vac += wv'@xv ----
  {
    f32x4 kac[2][4] = {};
    for (int ks = 0; ks < 8; ++ks) {
      bf16x8 ak[2], av[2], bf[4];
#pragma unroll
      for (int mt = 0; mt < 2; ++mt) {
        int row = (ob + mt * 16 + lm) * 256 + ks * 32 + lg * 8;
        ak[mt] = ld_g16(wkb + row);
        av[mt] = ld_g16(wvb + row);
      }
#pragma unroll
      for (int nt = 0; nt < 4; ++nt) {
        int p = nt * 16 + lm;
        bf[nt] = ld_s16(B1, p * 512 + (((ks * 32 + lg * 8) * 2) ^ ((p & 7) << 4)));
      }
      __builtin_amdgcn_s_setprio(1);
#pragma unroll
      for (int mt = 0; mt < 2; ++mt)
#pragma unroll
        for (int nt = 0; nt < 4; ++nt) {
          kac[mt][nt] = MFMA_BF16(ak[mt], bf[nt], kac[mt][nt]);
          vac[mt][nt] = MFMA_BF16(av[mt], bf[nt], vac[mt][nt]);
        }
      __builtin_amdgcn_s_setprio(0);
    }
    __syncthreads();  // B3: all waves done reading B1 (xv)
#pragma unroll
    for (int mt = 0; mt < 2; ++mt)
#pragma unroll
      for (int nt = 0; nt < 4; ++nt) {
        int o0 = ob + mt * 16 + lg * 4;
        int p = nt * 16 + lm;
        bf16x4 v4;
#pragma unroll
        for (int r = 0; r < 4; ++r) v4[r] = (__bf16)kac[mt][nt][r];
        *(bf16x4*)((char*)B1 + p * 512 + ((o0 * 2) ^ ((p & 7) << 4))) = v4;
      }
  }
  __syncthreads();  // B4: q,k visible to all waves

  // ---- S^T via swapped operands: D[kp][qp] ----
  f32x4 sacc[2][4] = {};
  for (int ks = 0; ks < 2; ++ks) {
    bf16x8 aq[2], bk[4];
#pragma unroll
    for (int mt = 0; mt < 2; ++mt) {
      int qp = half * 32 + mt * 16 + lm;
      aq[mt] = ld_s16(B0, qp * 512 + (((h * 64 + ks * 32 + lg * 8) * 2) ^ ((qp & 7) << 4)));
    }
#pragma unroll
    for (int nt = 0; nt < 4; ++nt) {
      int kp = nt * 16 + lm;
      bk[nt] = ld_s16(B1, kp * 512 + (((h * 64 + ks * 32 + lg * 8) * 2) ^ ((kp & 7) << 4)));
    }
    __builtin_amdgcn_s_setprio(1);
#pragma unroll
    for (int mt = 0; mt < 2; ++mt)
#pragma unroll
      for (int nt = 0; nt < 4; ++nt)
        sacc[mt][nt] = MFMA_BF16(bk[nt], aq[mt], sacc[mt][nt]);  // swapped -> D[kp][qp]
    __builtin_amdgcn_s_setprio(0);
  }

  // ---- softmax over kp: in-lane 16 values + 2 shfl rounds ----
  COMPILER_FENCE();
#pragma unroll
  for (int mt = 0; mt < 2; ++mt) {
    float mx = -3.0e38f;
#pragma unroll
    for (int nt = 0; nt < 4; ++nt)
#pragma unroll
      for (int r = 0; r < 4; ++r) {
        float s = sacc[mt][nt][r] * 0.125f;
        sacc[mt][nt][r] = s;
        bool valid = (nt < 3) || (lg == 0 && r == 0);   // kp < 49
        if (valid) mx = fmaxf(mx, s);
      }
    mx = fmaxf(mx, __shfl_xor(mx, 16));
    mx = fmaxf(mx, __shfl_xor(mx, 32));
    float sum = 0.f;
#pragma unroll
    for (int nt = 0; nt < 4; ++nt)
#pragma unroll
      for (int r = 0; r < 4; ++r) {
        bool valid = (nt < 3) || (lg == 0 && r == 0);
        float e = valid ? __expf(sacc[mt][nt][r] - mx) : 0.f;
        sacc[mt][nt][r] = e;
        sum += e;
      }
    sum += __shfl_xor(sum, 16);
    sum += __shfl_xor(sum, 32);
    float inv = 1.f / sum;
    // store P[qp][h*128 + kp] (overwrites q's head band; own rows only)
    int qp = half * 32 + mt * 16 + lm;
    int rowb = qp * 512 + h * 128;
    int sw = (qp & 7) << 4;
#pragma unroll
    for (int nt = 0; nt < 4; ++nt) {
      bf16x4 v4;
#pragma unroll
      for (int r = 0; r < 4; ++r) v4[r] = (__bf16)(sacc[mt][nt][r] * inv);
      int kp0 = nt * 16 + lg * 4;
      *(bf16x4*)((char*)B0 + rowb + ((kp0 * 2) ^ sw)) = v4;
    }
  }
  __syncthreads();  // B5: all S reads of B1(k) done before v overwrites it

  // ---- v = relu(vac + beta) -> B1 as [o][kp], rows 128 B (fits 32 KiB exactly) ----
  {
    float beta[2][4];
#pragma unroll
    for (int mt = 0; mt < 2; ++mt) {
      f32x4 bv = *(const f32x4*)(betav + ob + mt * 16 + lg * 4);
#pragma unroll
      for (int r = 0; r < 4; ++r) beta[mt][r] = bv[r];
    }
#pragma unroll
    for (int mt = 0; mt < 2; ++mt)
#pragma unroll
      for (int nt = 0; nt < 4; ++nt)
#pragma unroll
        for (int r = 0; r < 4; ++r) {
          int o = ob + mt * 16 + lg * 4 + r;
          int kp = nt * 16 + lm;
          float val = fmaxf(vac[mt][nt][r] + beta[mt][r], 0.f);
          int off = o * 128 + ((kp * 2) ^ ((o & 7) << 4));
          *(__bf16*)((char*)B1 + off) = (__bf16)val;
        }
  }
  __syncthreads();  // B6: v visible

  // ---- x_sp^T via swapped PV: D[o][qp] ----
  f32x4 oacc[4][2] = {};
  for (int ks = 0; ks < 2; ++ks) {
    bf16x8 pf[2], bv[4];
#pragma unroll
    for (int mt = 0; mt < 2; ++mt) {
      int qp = half * 32 + mt * 16 + lm;
      pf[mt] = ld_s16(B0, qp * 512 + h * 128 + (((ks * 32 + lg * 8) * 2) ^ ((qp & 7) << 4)));
    }
#pragma unroll
    for (int nt = 0; nt < 4; ++nt) {
      int o = h * 64 + nt * 16 + lm;
      bv[nt] = ld_s16(B1, o * 128 + (((ks * 32 + lg * 8) * 2) ^ ((o & 7) << 4)));
    }
    __builtin_amdgcn_s_setprio(1);
#pragma unroll
    for (int nt = 0; nt < 4; ++nt)
#pragma unroll
      for (int mt = 0; mt < 2; ++mt)
        oacc[nt][mt] = MFMA_BF16(bv[nt], pf[mt], oacc[nt][mt]);  // swapped -> D[o][qp]
    __builtin_amdgcn_s_setprio(0);
  }

  // ---- store x = IMP * x_sp (fp32); lanes sweep qp -> coalesced 28B runs ----
  const float IMP = (1.0f / 49.0f) / ((1.0f / 49.0f) + 1e-6f);
#pragma unroll
  for (int mt = 0; mt < 2; ++mt) {
    int qp = half * 32 + mt * 16 + lm;
    if (qp < 49) {
      int yy = y0 + qp / 7;
      int xx = x0 + qp % 7;
      size_t pix = (size_t)yy * 112 + xx;
#pragma unroll
      for (int nt = 0; nt < 4; ++nt)
#pragma unroll
        for (int r = 0; r < 4; ++r) {
          int o = h * 64 + nt * 16 + lg * 4 + r;
          xout[(size_t)(b * 256 + o) * 12544 + pix] = IMP * oacc[nt][mt][r];
        }
    }
  }
}

// ---------------- K2: depthwise 3x3 + BN2 + SiLU + pool (sliding reg window) ------
__global__ __launch_bounds__(256, 3) void k2_conv(
    const float* __restrict__ xin, const float* __restrict__ dww,
    const float* __restrict__ bn2s, const float* __restrict__ bn2b,
    __bf16* __restrict__ y1, float* __restrict__ pm)
{
  __shared__ __align__(16) float pl[12544];
  __shared__ float red[4];
  const int bc = blockIdx.x;
  const int c = bc & 255;
  const float* plane = xin + (size_t)bc * 12544;
  const int t = threadIdx.x;
  for (int i = t; i < 3136; i += 256)
    ((f32x4*)pl)[i] = ((const f32x4*)plane)[i];
  float wg[9];
#pragma unroll
  for (int i = 0; i < 9; ++i) wg[i] = dww[c * 9 + i];
  const float sc = bn2s[c], bi = bn2b[c];
  __syncthreads();

  const int x = t & 127;
  const int seg = t >> 7;
  float lsum = 0.f;
  if (x < 112) {
    const bool lok = x > 0, rok = x < 111;
    const int y0 = seg * 56;
    float m0, m1, m2, c0, c1, c2, p0, p1, p2;
    if (y0 == 0) {
      m0 = m1 = m2 = 0.f;
    } else {
      const float* rr = &pl[(y0 - 1) * 112 + x];
      m0 = lok ? rr[-1] : 0.f; m1 = rr[0]; m2 = rok ? rr[1] : 0.f;
    }
    {
      const float* rr = &pl[y0 * 112 + x];
      c0 = lok ? rr[-1] : 0.f; c1 = rr[0]; c2 = rok ? rr[1] : 0.f;
    }
#pragma unroll 4
    for (int y = y0; y < y0 + 56; ++y) {
      if (y < 111) {
        const float* rr = &pl[(y + 1) * 112 + x];
        p0 = lok ? rr[-1] : 0.f; p1 = rr[0]; p2 = rok ? rr[1] : 0.f;
      } else {
        p0 = p1 = p2 = 0.f;
      }
      float acc = m0 * wg[0] + m1 * wg[1] + m2 * wg[2]
                + c0 * wg[3] + c1 * wg[4] + c2 * wg[5]
                + p0 * wg[6] + p1 * wg[7] + p2 * wg[8];
      float u = acc * sc + bi;
      float sl = u / (1.f + __expf(-u));
      y1[(size_t)bc * 12544 + y * 112 + x] = (__bf16)sl;
      lsum += sl;
      m0 = c0; m1 = c1; m2 = c2;
      c0 = p0; c1 = p1; c2 = p2;
    }
  }
  lsum += __shfl_xor(lsum, 1);
  lsum += __shfl_xor(lsum, 2);
  lsum += __shfl_xor(lsum, 4);
  lsum += __shfl_xor(lsum, 8);
  lsum += __shfl_xor(lsum, 16);
  lsum += __shfl_xor(lsum, 32);
  if ((t & 63) == 0) red[t >> 6] = lsum;
  __syncthreads();
  if (t == 0) pm[bc] = (red[0] + red[1] + red[2] + red[3]) * (1.0f / 12544.0f);
}

// ---------------- K3: ECA gate ----------------
__global__ void k3_eca(const float* __restrict__ pm, const float* __restrict__ ecaw,
                       float* __restrict__ gate)
{
  int b = blockIdx.x, c = threadIdx.x;
  float p0 = (c > 0) ? pm[b * 256 + c - 1] : 0.f;
  float p1 = pm[b * 256 + c];
  float p2 = (c < 255) ? pm[b * 256 + c + 1] : 0.f;
  float a = ecaw[0] * p0 + ecaw[1] * p1 + ecaw[2] * p2;
  gate[b * 256 + c] = 1.f / (1.f + __expf(-a));
}

// ---------------- K4: out(fp32, in-place) = x + wp @ (y1 * gate) ----------------
__global__ __launch_bounds__(256, 3) void k4_out(
    const __bf16* __restrict__ y1, const float* __restrict__ gate,
    const __bf16* __restrict__ wpb, float* out_inout)
{
  __shared__ __align__(16) __bf16 bt[16384];  // [64 pos][256 ch] bf16, swizzled
  const int t = threadIdx.x;
  const int blk = blockIdx.x;
  const int b = blk / 196;
  const int s0 = (blk - b * 196) * 64;
  const int chunk = t & 7, crow = t >> 3;
#pragma unroll
  for (int cc = 0; cc < 8; ++cc) {
    int c = cc * 32 + crow;
    float g = gate[b * 256 + c];
    const __bf16* src = y1 + (size_t)(b * 256 + c) * 12544 + s0 + chunk * 8;
    bf16x8 v = *(const bf16x8*)src;
#pragma unroll
    for (int j = 0; j < 8; ++j) {
      int s = chunk * 8 + j;
      float f = (float)v[j] * g;
      *(__bf16*)((char*)bt + s * 512 + ((c * 2) ^ ((s & 7) << 4))) = (__bf16)f;
    }
  }
  __syncthreads();
  const int w = t >> 6, l = t & 63, lm = l & 15, lg = l >> 4;
  f32x4 acc[4][4] = {};
  proj_mfma(wpb, bt, acc, w, lm, lg);
#pragma unroll
  for (int mt = 0; mt < 4; ++mt)
#pragma unroll
    for (int nt = 0; nt < 4; ++nt)
#pragma unroll
      for (int r = 0; r < 4; ++r) {
        int o = w * 64 + mt * 16 + lg * 4 + r;
        int s = nt * 16 + lm;
        size_t idx = (size_t)(b * 256 + o) * 12544 + s0 + s;
        out_inout[idx] = out_inout[idx] + acc[mt][nt][r];
      }
}

// ---------------- launcher ----------------
extern "C" void kernel_launch(void* const* d_in, const int* in_sizes, int n_in,
                              void* d_out, int out_size, void* d_ws, size_t ws_size,
                              hipStream_t stream) {
  const float* x_edge = (const float*)d_in[0];
  const float* x_vit  = (const float*)d_in[1];
  const float* bn1_g  = (const float*)d_in[2];
  const float* bn1_b  = (const float*)d_in[3];
  const float* bn1_m  = (const float*)d_in[4];
  const float* bn1_v  = (const float*)d_in[5];
  const float* wq     = (const float*)d_in[6];
  const float* wk     = (const float*)d_in[7];
  const float* wv     = (const float*)d_in[8];
  const float* dw_w   = (const float*)d_in[9];
  const float* bn2_g  = (const float*)d_in[10];
  const float* bn2_b  = (const float*)d_in[11];
  const float* bn2_m  = (const float*)d_in[12];
  const float* bn2_v  = (const float*)d_in[13];
  const float* eca_w  = (const float*)d_in[14];
  const float* wp     = (const float*)d_in[15];

  float* out = (float*)d_out;  // reference output dtype is float32

  char* ws = (char*)d_ws;
  __bf16* tiles = (__bf16*)ws;
  __bf16* y1    = (__bf16*)ws;
  const size_t o1 = 102760448;
  __bf16* wqb  = (__bf16*)(ws + o1);
  __bf16* wkb  = (__bf16*)(ws + o1 + 131072);
  __bf16* wvb  = (__bf16*)(ws + o1 + 262144);
  __bf16* wpb  = (__bf16*)(ws + o1 + 393216);
  float*  betav= (float*)(ws + o1 + 524288);
  float*  bn2s = (float*)(ws + o1 + 525312);
  float*  bn2bb= (float*)(ws + o1 + 526336);
  float*  pm   = (float*)(ws + o1 + 527360);
  float*  gate = (float*)(ws + o1 + 543744);

  hipLaunchKernelGGL(k0_setup, dim3(256), dim3(256), 0, stream,
                     wq, wk, wv, wp, bn1_g, bn1_b, bn1_m, bn1_v,
                     bn2_g, bn2_b, bn2_m, bn2_v,
                     wqb, wkb, wvb, wpb, betav, bn2s, bn2bb);
  for (int hb = 0; hb < 16; hb += 8) {
    hipLaunchKernelGGL(k_pre, dim3(1024), dim3(256), 0, stream,
                       x_edge, x_vit, tiles, hb);
    hipLaunchKernelGGL(k1_attn, dim3(2048), dim3(512), 0, stream,
                       tiles, wqb, wkb, wvb, betav, out, hb);
  }
  hipLaunchKernelGGL(k2_conv, dim3(4096), dim3(256), 0, stream,
                     out, dw_w, bn2s, bn2bb, y1, pm);
  hipLaunchKernelGGL(k3_eca, dim3(16), dim3(256), 0, stream, pm, eca_w, gate);
  hipLaunchKernelGGL(k4_out, dim3(3136), dim3(256), 0, stream,
                     y1, gate, wpb, out);
}